// Round 1
// baseline (1320.034 us; speedup 1.0000x reference)
//
#include <hip/hip_runtime.h>
#include <math.h>

// Problem constants (fixed by setup_inputs)
#define B_   8
#define C_   768
#define T_   1024      // H*W = 32*32
#define NH_  12
#define DH_  64
#define BT_  (B_*T_)   // 8192

// ---------------------------------------------------------------------------
// Kernel 1: LayerNorm over C with implicit (B,C,T) -> (B*T, C) transpose.
// One block per (b,t) row; 256 threads, 3 elements each.
// Reads x strided (T*4B apart per lane) -- absorbed by L2/L3 (25 MB total).
// Writes xn coalesced (C contiguous).
// ---------------------------------------------------------------------------
__global__ __launch_bounds__(256) void ln_kernel(const float* __restrict__ x,
                                                 const float* __restrict__ gamma,
                                                 const float* __restrict__ beta,
                                                 float* __restrict__ xn) {
    int row = blockIdx.x;        // b*T + t
    int b = row >> 10;           // T_ = 1024
    int t = row & 1023;
    int tid = threadIdx.x;
    const float* xb = x + (size_t)b * C_ * T_ + t;
    float v0 = xb[(size_t)(tid      ) * T_];
    float v1 = xb[(size_t)(tid + 256) * T_];
    float v2 = xb[(size_t)(tid + 512) * T_];
    float s  = v0 + v1 + v2;
    float sq = v0 * v0 + v1 * v1 + v2 * v2;
    #pragma unroll
    for (int m = 1; m < 64; m <<= 1) {
        s  += __shfl_xor(s,  m);
        sq += __shfl_xor(sq, m);
    }
    __shared__ float ss[4], ssq[4];
    int wid = tid >> 6;
    if ((tid & 63) == 0) { ss[wid] = s; ssq[wid] = sq; }
    __syncthreads();
    s  = ss[0] + ss[1] + ss[2] + ss[3];
    sq = ssq[0] + ssq[1] + ssq[2] + ssq[3];
    float mu   = s * (1.0f / 768.0f);
    float var  = sq * (1.0f / 768.0f) - mu * mu;
    float rstd = 1.0f / sqrtf(var + 1e-5f);
    float* o = xn + (size_t)row * C_;
    o[tid      ] = (v0 - mu) * rstd * gamma[tid      ] + beta[tid      ];
    o[tid + 256] = (v1 - mu) * rstd * gamma[tid + 256] + beta[tid + 256];
    o[tid + 512] = (v2 - mu) * rstd * gamma[tid + 512] + beta[tid + 512];
}

// ---------------------------------------------------------------------------
// Kernel 2: fused Q/K/V/Gate GEMM.  out[m][n] = sum_k xn[m][k]*W[n][k] + b[n]
// M=8192, K=768, four N=768 weight mats treated as by in [0,48).
// 64x64 block tile, BK=16, 256 threads, 4x4 microtile, LDS stride 68.
// ---------------------------------------------------------------------------
__global__ __launch_bounds__(256) void qkvg_kernel(
    const float* __restrict__ xn,
    const float* __restrict__ Wq, const float* __restrict__ bq,
    const float* __restrict__ Wk, const float* __restrict__ bk,
    const float* __restrict__ Wv, const float* __restrict__ bv,
    const float* __restrict__ Wg, const float* __restrict__ bg,
    float* __restrict__ q, float* __restrict__ k,
    float* __restrict__ v, float* __restrict__ g) {
    int bx = blockIdx.x;            // m tile 0..127
    int by = blockIdx.y;            // 0..47
    int mat = by / 12;
    int n0  = (by % 12) * 64;
    int m0  = bx * 64;
    const float* W; const float* bias; float* out;
    switch (mat) {
        case 0:  W = Wq; bias = bq; out = q; break;
        case 1:  W = Wk; bias = bk; out = k; break;
        case 2:  W = Wv; bias = bv; out = v; break;
        default: W = Wg; bias = bg; out = g; break;
    }
    __shared__ float As[16][68];   // [k][m], transposed
    __shared__ float Bs[16][68];   // [k][n], transposed
    int tid = threadIdx.x;
    int tx = tid & 15, ty = tid >> 4;
    int lr = tid >> 2;             // staging row 0..63
    int lc = (tid & 3) * 4;        // staging col 0,4,8,12
    float acc[4][4] = {};
    for (int k0 = 0; k0 < 768; k0 += 16) {
        float4 a4 = *(const float4*)(xn + (size_t)(m0 + lr) * 768 + k0 + lc);
        float4 b4 = *(const float4*)(W  + (size_t)(n0 + lr) * 768 + k0 + lc);
        As[lc + 0][lr] = a4.x; As[lc + 1][lr] = a4.y;
        As[lc + 2][lr] = a4.z; As[lc + 3][lr] = a4.w;
        Bs[lc + 0][lr] = b4.x; Bs[lc + 1][lr] = b4.y;
        Bs[lc + 2][lr] = b4.z; Bs[lc + 3][lr] = b4.w;
        __syncthreads();
        #pragma unroll
        for (int kk = 0; kk < 16; ++kk) {
            float4 av = *(const float4*)&As[kk][ty * 4];
            float4 bv4 = *(const float4*)&Bs[kk][tx * 4];
            float aa[4] = {av.x, av.y, av.z, av.w};
            float bb[4] = {bv4.x, bv4.y, bv4.z, bv4.w};
            #pragma unroll
            for (int i = 0; i < 4; ++i)
                #pragma unroll
                for (int j = 0; j < 4; ++j)
                    acc[i][j] = fmaf(aa[i], bb[j], acc[i][j]);
        }
        __syncthreads();
    }
    #pragma unroll
    for (int i = 0; i < 4; ++i) {
        float4 r;
        r.x = acc[i][0] + bias[n0 + tx * 4 + 0];
        r.y = acc[i][1] + bias[n0 + tx * 4 + 1];
        r.z = acc[i][2] + bias[n0 + tx * 4 + 2];
        r.w = acc[i][3] + bias[n0 + tx * 4 + 3];
        *(float4*)(out + (size_t)(m0 + ty * 4 + i) * 768 + n0 + tx * 4) = r;
    }
}

// ---------------------------------------------------------------------------
// Kernel 3: flash-style attention + sigmoid gate, per (q-tile=64, head, batch).
// Online softmax; K LDS buffer reused for V (52 KB LDS total).
// Writes gated y back into the xn workspace slot (xn no longer needed).
// ---------------------------------------------------------------------------
__global__ __launch_bounds__(256) void attn_kernel(
    const float* __restrict__ q, const float* __restrict__ k,
    const float* __restrict__ v, const float* __restrict__ g,
    float* __restrict__ y) {
    int qt = blockIdx.x;   // 0..15
    int h  = blockIdx.y;   // 0..11
    int b  = blockIdx.z;   // 0..7
    __shared__ float Qs[64][68];
    __shared__ float KVs[64][68];  // K tile, then overwritten with V tile
    __shared__ float Ps[64][68];
    int tid = threadIdx.x;
    int tx = tid & 15, ty = tid >> 4;
    size_t headoff = (size_t)h * 64;
    const float* qg = q + (size_t)(b * 1024 + qt * 64) * 768 + headoff;
    // Load + scale Q tile (scale = 1/sqrt(64))
    #pragma unroll
    for (int it = 0; it < 4; ++it) {
        int idx = tid + it * 256;          // 0..1023
        int r = idx >> 4, c4 = (idx & 15) * 4;
        float4 qv = *(const float4*)(qg + (size_t)r * 768 + c4);
        qv.x *= 0.125f; qv.y *= 0.125f; qv.z *= 0.125f; qv.w *= 0.125f;
        *(float4*)&Qs[r][c4] = qv;
    }
    float m_i[4], l_i[4], Oacc[4][4] = {};
    #pragma unroll
    for (int i = 0; i < 4; ++i) { m_i[i] = -1e30f; l_i[i] = 0.0f; }
    const float* kg = k + (size_t)(b * 1024) * 768 + headoff;
    const float* vg = v + (size_t)(b * 1024) * 768 + headoff;

    for (int st = 0; st < 16; ++st) {
        // stage K tile
        #pragma unroll
        for (int it = 0; it < 4; ++it) {
            int idx = tid + it * 256;
            int r = idx >> 4, c4 = (idx & 15) * 4;
            *(float4*)&KVs[r][c4] =
                *(const float4*)(kg + (size_t)(st * 64 + r) * 768 + c4);
        }
        __syncthreads();
        // S = Q K^T (64x64), 4x4 per thread
        float sacc[4][4] = {};
        #pragma unroll
        for (int d0 = 0; d0 < 64; d0 += 4) {
            float4 qa[4], kb[4];
            #pragma unroll
            for (int i = 0; i < 4; ++i) qa[i] = *(const float4*)&Qs[ty * 4 + i][d0];
            #pragma unroll
            for (int j = 0; j < 4; ++j) kb[j] = *(const float4*)&KVs[tx * 4 + j][d0];
            #pragma unroll
            for (int i = 0; i < 4; ++i)
                #pragma unroll
                for (int j = 0; j < 4; ++j)
                    sacc[i][j] += qa[i].x * kb[j].x + qa[i].y * kb[j].y +
                                  qa[i].z * kb[j].z + qa[i].w * kb[j].w;
        }
        // online softmax update (rows live across the 16 lanes sharing ty)
        #pragma unroll
        for (int i = 0; i < 4; ++i) {
            float mx = fmaxf(fmaxf(sacc[i][0], sacc[i][1]),
                             fmaxf(sacc[i][2], sacc[i][3]));
            #pragma unroll
            for (int msk = 1; msk < 16; msk <<= 1) mx = fmaxf(mx, __shfl_xor(mx, msk));
            float m_new = fmaxf(m_i[i], mx);
            float alpha = __expf(m_i[i] - m_new);
            float p0 = __expf(sacc[i][0] - m_new);
            float p1 = __expf(sacc[i][1] - m_new);
            float p2 = __expf(sacc[i][2] - m_new);
            float p3 = __expf(sacc[i][3] - m_new);
            float rs = p0 + p1 + p2 + p3;
            #pragma unroll
            for (int msk = 1; msk < 16; msk <<= 1) rs += __shfl_xor(rs, msk);
            l_i[i] = l_i[i] * alpha + rs;
            m_i[i] = m_new;
            #pragma unroll
            for (int j = 0; j < 4; ++j) Oacc[i][j] *= alpha;
            *(float4*)&Ps[ty * 4 + i][tx * 4] = make_float4(p0, p1, p2, p3);
        }
        __syncthreads();   // K reads done, P visible
        // stage V tile into same buffer
        #pragma unroll
        for (int it = 0; it < 4; ++it) {
            int idx = tid + it * 256;
            int r = idx >> 4, c4 = (idx & 15) * 4;
            *(float4*)&KVs[r][c4] =
                *(const float4*)(vg + (size_t)(st * 64 + r) * 768 + c4);
        }
        __syncthreads();
        // O += P V
        #pragma unroll
        for (int s0 = 0; s0 < 64; s0 += 4) {
            float4 pa[4], vb[4];
            #pragma unroll
            for (int i = 0; i < 4; ++i) pa[i] = *(const float4*)&Ps[ty * 4 + i][s0];
            #pragma unroll
            for (int ss = 0; ss < 4; ++ss) vb[ss] = *(const float4*)&KVs[s0 + ss][tx * 4];
            #pragma unroll
            for (int i = 0; i < 4; ++i) {
                float pv[4] = {pa[i].x, pa[i].y, pa[i].z, pa[i].w};
                #pragma unroll
                for (int ss = 0; ss < 4; ++ss) {
                    Oacc[i][0] = fmaf(pv[ss], vb[ss].x, Oacc[i][0]);
                    Oacc[i][1] = fmaf(pv[ss], vb[ss].y, Oacc[i][1]);
                    Oacc[i][2] = fmaf(pv[ss], vb[ss].z, Oacc[i][2]);
                    Oacc[i][3] = fmaf(pv[ss], vb[ss].w, Oacc[i][3]);
                }
            }
        }
        __syncthreads();   // P/V reads done before next stage
    }
    // epilogue: normalize, sigmoid gate, write y
    const float* gg = g + (size_t)(b * 1024 + qt * 64) * 768 + headoff;
    float* yo = y + (size_t)(b * 1024 + qt * 64) * 768 + headoff;
    #pragma unroll
    for (int i = 0; i < 4; ++i) {
        float inv = 1.0f / l_i[i];
        float4 gv = *(const float4*)(gg + (size_t)(ty * 4 + i) * 768 + tx * 4);
        float4 r;
        r.x = Oacc[i][0] * inv * (1.0f / (1.0f + __expf(-gv.x)));
        r.y = Oacc[i][1] * inv * (1.0f / (1.0f + __expf(-gv.y)));
        r.z = Oacc[i][2] * inv * (1.0f / (1.0f + __expf(-gv.z)));
        r.w = Oacc[i][3] * inv * (1.0f / (1.0f + __expf(-gv.w)));
        *(float4*)(yo + (size_t)(ty * 4 + i) * 768 + tx * 4) = r;
    }
}

// ---------------------------------------------------------------------------
// Kernel 4: out = y @ Wo^T + bo, transposed back to (B, C, T).
// A = Wo (c rows), B = y (t rows) so stores are contiguous along t.
// ---------------------------------------------------------------------------
__global__ __launch_bounds__(256) void out_kernel(
    const float* __restrict__ y, const float* __restrict__ Wo,
    const float* __restrict__ bo, float* __restrict__ out) {
    int cx = blockIdx.x;   // 0..11  c tile
    int my = blockIdx.y;   // 0..127 m tile over B*T
    int c0 = cx * 64;
    int m0 = my * 64;
    __shared__ float As[16][68];   // Wo [k][c]
    __shared__ float Bs[16][68];   // y  [k][m]
    int tid = threadIdx.x;
    int tx = tid & 15, ty = tid >> 4;
    int lr = tid >> 2;
    int lc = (tid & 3) * 4;
    float acc[4][4] = {};
    for (int k0 = 0; k0 < 768; k0 += 16) {
        float4 a4 = *(const float4*)(Wo + (size_t)(c0 + lr) * 768 + k0 + lc);
        float4 b4 = *(const float4*)(y  + (size_t)(m0 + lr) * 768 + k0 + lc);
        As[lc + 0][lr] = a4.x; As[lc + 1][lr] = a4.y;
        As[lc + 2][lr] = a4.z; As[lc + 3][lr] = a4.w;
        Bs[lc + 0][lr] = b4.x; Bs[lc + 1][lr] = b4.y;
        Bs[lc + 2][lr] = b4.z; Bs[lc + 3][lr] = b4.w;
        __syncthreads();
        #pragma unroll
        for (int kk = 0; kk < 16; ++kk) {
            float4 av = *(const float4*)&As[kk][ty * 4];
            float4 bv4 = *(const float4*)&Bs[kk][tx * 4];
            float aa[4] = {av.x, av.y, av.z, av.w};
            float bb[4] = {bv4.x, bv4.y, bv4.z, bv4.w};
            #pragma unroll
            for (int i = 0; i < 4; ++i)
                #pragma unroll
                for (int j = 0; j < 4; ++j)
                    acc[i][j] = fmaf(aa[i], bb[j], acc[i][j]);
        }
        __syncthreads();
    }
    int b = m0 >> 10;
    int t0b = (m0 & 1023) + tx * 4;
    #pragma unroll
    for (int i = 0; i < 4; ++i) {
        float bc = bo[c0 + ty * 4 + i];
        float4 r = make_float4(acc[i][0] + bc, acc[i][1] + bc,
                               acc[i][2] + bc, acc[i][3] + bc);
        *(float4*)(out + ((size_t)b * 768 + c0 + ty * 4 + i) * 1024 + t0b) = r;
    }
}

extern "C" void kernel_launch(void* const* d_in, const int* in_sizes, int n_in,
                              void* d_out, int out_size, void* d_ws, size_t ws_size,
                              hipStream_t stream) {
    const float* x     = (const float*)d_in[0];
    const float* Wq    = (const float*)d_in[1];
    const float* bq    = (const float*)d_in[2];
    const float* Wk    = (const float*)d_in[3];
    const float* bk    = (const float*)d_in[4];
    const float* Wv    = (const float*)d_in[5];
    const float* bv    = (const float*)d_in[6];
    const float* Wo    = (const float*)d_in[7];
    const float* bo    = (const float*)d_in[8];
    const float* Wg    = (const float*)d_in[9];
    const float* bg    = (const float*)d_in[10];
    const float* gamma = (const float*)d_in[11];
    const float* beta  = (const float*)d_in[12];
    float* out = (float*)d_out;

    // workspace layout (fp32): xn | q | k | v | g   (y overwrites xn)
    const size_t S = (size_t)BT_ * C_;   // 6.29M elements each
    float* xn = (float*)d_ws;
    float* q  = xn + S;
    float* k  = q + S;
    float* v  = k + S;
    float* g  = v + S;

    ln_kernel<<<BT_, 256, 0, stream>>>(x, gamma, beta, xn);
    qkvg_kernel<<<dim3(128, 48), 256, 0, stream>>>(xn, Wq, bq, Wk, bk, Wv, bv,
                                                   Wg, bg, q, k, v, g);
    attn_kernel<<<dim3(16, 12, 8), 256, 0, stream>>>(q, k, v, g, xn);  // y -> xn
    out_kernel<<<dim3(12, 128), 256, 0, stream>>>(xn, Wo, bo, out);
}

// Round 2
// 1208.243 us; speedup vs baseline: 1.0925x; 1.0925x over previous
//
#include <hip/hip_runtime.h>
#include <math.h>

// Problem constants (fixed by setup_inputs)
#define B_   8
#define C_   768
#define T_   1024      // H*W = 32*32
#define NH_  12
#define DH_  64
#define BT_  (B_*T_)   // 8192

// ---------------------------------------------------------------------------
// Kernel 1: LayerNorm over C with implicit (B,C,T) -> (B*T, C) transpose.
// ---------------------------------------------------------------------------
__global__ __launch_bounds__(256) void ln_kernel(const float* __restrict__ x,
                                                 const float* __restrict__ gamma,
                                                 const float* __restrict__ beta,
                                                 float* __restrict__ xn) {
    int row = blockIdx.x;        // b*T + t
    int b = row >> 10;           // T_ = 1024
    int t = row & 1023;
    int tid = threadIdx.x;
    const float* xb = x + (size_t)b * C_ * T_ + t;
    float v0 = xb[(size_t)(tid      ) * T_];
    float v1 = xb[(size_t)(tid + 256) * T_];
    float v2 = xb[(size_t)(tid + 512) * T_];
    float s  = v0 + v1 + v2;
    float sq = v0 * v0 + v1 * v1 + v2 * v2;
    #pragma unroll
    for (int m = 1; m < 64; m <<= 1) {
        s  += __shfl_xor(s,  m);
        sq += __shfl_xor(sq, m);
    }
    __shared__ float ss[4], ssq[4];
    int wid = tid >> 6;
    if ((tid & 63) == 0) { ss[wid] = s; ssq[wid] = sq; }
    __syncthreads();
    s  = ss[0] + ss[1] + ss[2] + ss[3];
    sq = ssq[0] + ssq[1] + ssq[2] + ssq[3];
    float mu   = s * (1.0f / 768.0f);
    float var  = sq * (1.0f / 768.0f) - mu * mu;
    float rstd = 1.0f / sqrtf(var + 1e-5f);
    float* o = xn + (size_t)row * C_;
    o[tid      ] = (v0 - mu) * rstd * gamma[tid      ] + beta[tid      ];
    o[tid + 256] = (v1 - mu) * rstd * gamma[tid + 256] + beta[tid + 256];
    o[tid + 512] = (v2 - mu) * rstd * gamma[tid + 512] + beta[tid + 512];
}

// ---------------------------------------------------------------------------
// Kernel 2: fused Q/K/V/Gate GEMM.  out[m][n] = sum_k xn[m][k]*W[n][k] + b[n]
// 128x128 block tile, BK=16, 256 threads, 8x8 microtile, LDS stride 132.
// FLOP:LDS-byte = 2.0 (vs 1.0 for 4x4) -- LDS-BW headroom for the VALU.
// ---------------------------------------------------------------------------
__global__ __launch_bounds__(256) void qkvg_kernel(
    const float* __restrict__ xn,
    const float* __restrict__ Wq, const float* __restrict__ bq,
    const float* __restrict__ Wk, const float* __restrict__ bk,
    const float* __restrict__ Wv, const float* __restrict__ bv,
    const float* __restrict__ Wg, const float* __restrict__ bg,
    float* __restrict__ q, float* __restrict__ k,
    float* __restrict__ v, float* __restrict__ g) {
    int bx = blockIdx.x;            // m tile 0..63
    int by = blockIdx.y;            // 0..23
    int mat = by / 6;
    int n0  = (by % 6) * 128;
    int m0  = bx * 128;
    const float* W; const float* bias; float* out;
    switch (mat) {
        case 0:  W = Wq; bias = bq; out = q; break;
        case 1:  W = Wk; bias = bk; out = k; break;
        case 2:  W = Wv; bias = bv; out = v; break;
        default: W = Wg; bias = bg; out = g; break;
    }
    __shared__ float As[16][132];   // [k][m], transposed
    __shared__ float Bs[16][132];   // [k][n], transposed
    int tid = threadIdx.x;
    int tx = tid & 15, ty = tid >> 4;
    int srow = tid >> 2;            // 0..63
    int scol = (tid & 3) * 4;       // 0,4,8,12
    const float* aA = xn + (size_t)(m0 + srow) * 768 + scol;
    const float* aB = W  + (size_t)(n0 + srow) * 768 + scol;
    float acc[8][8] = {};
    for (int k0 = 0; k0 < 768; k0 += 16) {
        float4 a0 = *(const float4*)(aA + k0);
        float4 a1 = *(const float4*)(aA + (size_t)64 * 768 + k0);
        float4 b0 = *(const float4*)(aB + k0);
        float4 b1 = *(const float4*)(aB + (size_t)64 * 768 + k0);
        As[scol + 0][srow] = a0.x; As[scol + 1][srow] = a0.y;
        As[scol + 2][srow] = a0.z; As[scol + 3][srow] = a0.w;
        As[scol + 0][srow + 64] = a1.x; As[scol + 1][srow + 64] = a1.y;
        As[scol + 2][srow + 64] = a1.z; As[scol + 3][srow + 64] = a1.w;
        Bs[scol + 0][srow] = b0.x; Bs[scol + 1][srow] = b0.y;
        Bs[scol + 2][srow] = b0.z; Bs[scol + 3][srow] = b0.w;
        Bs[scol + 0][srow + 64] = b1.x; Bs[scol + 1][srow + 64] = b1.y;
        Bs[scol + 2][srow + 64] = b1.z; Bs[scol + 3][srow + 64] = b1.w;
        __syncthreads();
        #pragma unroll
        for (int kk = 0; kk < 16; ++kk) {
            float a[8], b[8];
            *(float4*)&a[0] = *(const float4*)&As[kk][ty * 4];
            *(float4*)&a[4] = *(const float4*)&As[kk][64 + ty * 4];
            *(float4*)&b[0] = *(const float4*)&Bs[kk][tx * 4];
            *(float4*)&b[4] = *(const float4*)&Bs[kk][64 + tx * 4];
            #pragma unroll
            for (int i = 0; i < 8; ++i)
                #pragma unroll
                for (int j = 0; j < 8; ++j)
                    acc[i][j] = fmaf(a[i], b[j], acc[i][j]);
        }
        __syncthreads();
    }
    float bj[8];
    #pragma unroll
    for (int j = 0; j < 8; ++j)
        bj[j] = bias[n0 + (j >> 2) * 64 + tx * 4 + (j & 3)];
    #pragma unroll
    for (int i = 0; i < 8; ++i) {
        int row = m0 + (i >> 2) * 64 + ty * 4 + (i & 3);
        float4 r0 = make_float4(acc[i][0] + bj[0], acc[i][1] + bj[1],
                                acc[i][2] + bj[2], acc[i][3] + bj[3]);
        float4 r1 = make_float4(acc[i][4] + bj[4], acc[i][5] + bj[5],
                                acc[i][6] + bj[6], acc[i][7] + bj[7]);
        *(float4*)(out + (size_t)row * 768 + n0 + tx * 4) = r0;
        *(float4*)(out + (size_t)row * 768 + n0 + 64 + tx * 4) = r1;
    }
}

// ---------------------------------------------------------------------------
// Kernel 3: flash-style attention + sigmoid gate.
// S-columns owned as {j*16+tx} so K-fragment LDS reads spread evenly across
// all 8 bank-quads (was 2 of 8 -> the 7.55e7-cycle conflict hotspot).
// ---------------------------------------------------------------------------
__global__ __launch_bounds__(256) void attn_kernel(
    const float* __restrict__ q, const float* __restrict__ k,
    const float* __restrict__ v, const float* __restrict__ g,
    float* __restrict__ y) {
    int qt = blockIdx.x;   // 0..15
    int h  = blockIdx.y;   // 0..11
    int b  = blockIdx.z;   // 0..7
    __shared__ float Qs[64][68];
    __shared__ float KVs[64][68];  // K tile, then overwritten with V tile
    __shared__ float Ps[64][68];
    int tid = threadIdx.x;
    int tx = tid & 15, ty = tid >> 4;
    size_t headoff = (size_t)h * 64;
    const float* qg = q + (size_t)(b * 1024 + qt * 64) * 768 + headoff;
    #pragma unroll
    for (int it = 0; it < 4; ++it) {
        int idx = tid + it * 256;          // 0..1023
        int r = idx >> 4, c4 = (idx & 15) * 4;
        float4 qv = *(const float4*)(qg + (size_t)r * 768 + c4);
        qv.x *= 0.125f; qv.y *= 0.125f; qv.z *= 0.125f; qv.w *= 0.125f;
        *(float4*)&Qs[r][c4] = qv;
    }
    float m_i[4], l_i[4], Oacc[4][4] = {};
    #pragma unroll
    for (int i = 0; i < 4; ++i) { m_i[i] = -1e30f; l_i[i] = 0.0f; }
    const float* kg = k + (size_t)(b * 1024) * 768 + headoff;
    const float* vg = v + (size_t)(b * 1024) * 768 + headoff;

    for (int st = 0; st < 16; ++st) {
        // stage K tile
        #pragma unroll
        for (int it = 0; it < 4; ++it) {
            int idx = tid + it * 256;
            int r = idx >> 4, c4 = (idx & 15) * 4;
            *(float4*)&KVs[r][c4] =
                *(const float4*)(kg + (size_t)(st * 64 + r) * 768 + c4);
        }
        __syncthreads();
        // S = Q K^T; thread owns rows {ty*4+i}, cols {j*16+tx}
        float sacc[4][4] = {};
        #pragma unroll
        for (int d0 = 0; d0 < 64; d0 += 4) {
            float4 qa[4], kb[4];
            #pragma unroll
            for (int i = 0; i < 4; ++i) qa[i] = *(const float4*)&Qs[ty * 4 + i][d0];
            #pragma unroll
            for (int j = 0; j < 4; ++j) kb[j] = *(const float4*)&KVs[j * 16 + tx][d0];
            #pragma unroll
            for (int i = 0; i < 4; ++i)
                #pragma unroll
                for (int j = 0; j < 4; ++j)
                    sacc[i][j] += qa[i].x * kb[j].x + qa[i].y * kb[j].y +
                                  qa[i].z * kb[j].z + qa[i].w * kb[j].w;
        }
        // online softmax update (row spread across the 16 lanes sharing ty)
        #pragma unroll
        for (int i = 0; i < 4; ++i) {
            float mx = fmaxf(fmaxf(sacc[i][0], sacc[i][1]),
                             fmaxf(sacc[i][2], sacc[i][3]));
            #pragma unroll
            for (int msk = 1; msk < 16; msk <<= 1) mx = fmaxf(mx, __shfl_xor(mx, msk));
            float m_new = fmaxf(m_i[i], mx);
            float alpha = __expf(m_i[i] - m_new);
            float p0 = __expf(sacc[i][0] - m_new);
            float p1 = __expf(sacc[i][1] - m_new);
            float p2 = __expf(sacc[i][2] - m_new);
            float p3 = __expf(sacc[i][3] - m_new);
            float rs = p0 + p1 + p2 + p3;
            #pragma unroll
            for (int msk = 1; msk < 16; msk <<= 1) rs += __shfl_xor(rs, msk);
            l_i[i] = l_i[i] * alpha + rs;
            m_i[i] = m_new;
            #pragma unroll
            for (int j = 0; j < 4; ++j) Oacc[i][j] *= alpha;
            Ps[ty * 4 + i][ 0 + tx] = p0;
            Ps[ty * 4 + i][16 + tx] = p1;
            Ps[ty * 4 + i][32 + tx] = p2;
            Ps[ty * 4 + i][48 + tx] = p3;
        }
        __syncthreads();   // K reads done, P visible
        // stage V tile into same buffer
        #pragma unroll
        for (int it = 0; it < 4; ++it) {
            int idx = tid + it * 256;
            int r = idx >> 4, c4 = (idx & 15) * 4;
            *(float4*)&KVs[r][c4] =
                *(const float4*)(vg + (size_t)(st * 64 + r) * 768 + c4);
        }
        __syncthreads();
        // O += P V   (thread cols of O are {tx*4..tx*4+3} in d)
        #pragma unroll
        for (int s0 = 0; s0 < 64; s0 += 4) {
            float4 pa[4], vb[4];
            #pragma unroll
            for (int i = 0; i < 4; ++i) pa[i] = *(const float4*)&Ps[ty * 4 + i][s0];
            #pragma unroll
            for (int ss = 0; ss < 4; ++ss) vb[ss] = *(const float4*)&KVs[s0 + ss][tx * 4];
            #pragma unroll
            for (int i = 0; i < 4; ++i) {
                float pv[4] = {pa[i].x, pa[i].y, pa[i].z, pa[i].w};
                #pragma unroll
                for (int ss = 0; ss < 4; ++ss) {
                    Oacc[i][0] = fmaf(pv[ss], vb[ss].x, Oacc[i][0]);
                    Oacc[i][1] = fmaf(pv[ss], vb[ss].y, Oacc[i][1]);
                    Oacc[i][2] = fmaf(pv[ss], vb[ss].z, Oacc[i][2]);
                    Oacc[i][3] = fmaf(pv[ss], vb[ss].w, Oacc[i][3]);
                }
            }
        }
        __syncthreads();   // P/V reads done before next stage
    }
    // epilogue: normalize, sigmoid gate, write y
    const float* gg = g + (size_t)(b * 1024 + qt * 64) * 768 + headoff;
    float* yo = y + (size_t)(b * 1024 + qt * 64) * 768 + headoff;
    #pragma unroll
    for (int i = 0; i < 4; ++i) {
        float inv = 1.0f / l_i[i];
        float4 gv = *(const float4*)(gg + (size_t)(ty * 4 + i) * 768 + tx * 4);
        float4 r;
        r.x = Oacc[i][0] * inv * (1.0f / (1.0f + __expf(-gv.x)));
        r.y = Oacc[i][1] * inv * (1.0f / (1.0f + __expf(-gv.y)));
        r.z = Oacc[i][2] * inv * (1.0f / (1.0f + __expf(-gv.z)));
        r.w = Oacc[i][3] * inv * (1.0f / (1.0f + __expf(-gv.w)));
        *(float4*)(yo + (size_t)(ty * 4 + i) * 768 + tx * 4) = r;
    }
}

// ---------------------------------------------------------------------------
// Kernel 4: out = y @ Wo^T + bo, transposed back to (B, C, T).
// 128x128 tile, 8x8 microtile.  A = Wo (c rows), B = y (t rows).
// ---------------------------------------------------------------------------
__global__ __launch_bounds__(256) void out_kernel(
    const float* __restrict__ y, const float* __restrict__ Wo,
    const float* __restrict__ bo, float* __restrict__ out) {
    int cx = blockIdx.x;   // 0..5   c tile
    int my = blockIdx.y;   // 0..63  m tile over B*T
    int c0 = cx * 128;
    int m0 = my * 128;
    __shared__ float As[16][132];   // Wo [k][c]
    __shared__ float Bs[16][132];   // y  [k][m]
    int tid = threadIdx.x;
    int tx = tid & 15, ty = tid >> 4;
    int srow = tid >> 2;
    int scol = (tid & 3) * 4;
    const float* aA = Wo + (size_t)(c0 + srow) * 768 + scol;
    const float* aB = y  + (size_t)(m0 + srow) * 768 + scol;
    float acc[8][8] = {};
    for (int k0 = 0; k0 < 768; k0 += 16) {
        float4 a0 = *(const float4*)(aA + k0);
        float4 a1 = *(const float4*)(aA + (size_t)64 * 768 + k0);
        float4 b0 = *(const float4*)(aB + k0);
        float4 b1 = *(const float4*)(aB + (size_t)64 * 768 + k0);
        As[scol + 0][srow] = a0.x; As[scol + 1][srow] = a0.y;
        As[scol + 2][srow] = a0.z; As[scol + 3][srow] = a0.w;
        As[scol + 0][srow + 64] = a1.x; As[scol + 1][srow + 64] = a1.y;
        As[scol + 2][srow + 64] = a1.z; As[scol + 3][srow + 64] = a1.w;
        Bs[scol + 0][srow] = b0.x; Bs[scol + 1][srow] = b0.y;
        Bs[scol + 2][srow] = b0.z; Bs[scol + 3][srow] = b0.w;
        Bs[scol + 0][srow + 64] = b1.x; Bs[scol + 1][srow + 64] = b1.y;
        Bs[scol + 2][srow + 64] = b1.z; Bs[scol + 3][srow + 64] = b1.w;
        __syncthreads();
        #pragma unroll
        for (int kk = 0; kk < 16; ++kk) {
            float a[8], b[8];
            *(float4*)&a[0] = *(const float4*)&As[kk][ty * 4];
            *(float4*)&a[4] = *(const float4*)&As[kk][64 + ty * 4];
            *(float4*)&b[0] = *(const float4*)&Bs[kk][tx * 4];
            *(float4*)&b[4] = *(const float4*)&Bs[kk][64 + tx * 4];
            #pragma unroll
            for (int i = 0; i < 8; ++i)
                #pragma unroll
                for (int j = 0; j < 8; ++j)
                    acc[i][j] = fmaf(a[i], b[j], acc[i][j]);
        }
        __syncthreads();
    }
    int b = m0 >> 10;
    int t0 = m0 & 1023;
    #pragma unroll
    for (int i = 0; i < 8; ++i) {
        int row = c0 + (i >> 2) * 64 + ty * 4 + (i & 3);
        float bc = bo[row];
        float4 r0 = make_float4(acc[i][0] + bc, acc[i][1] + bc,
                                acc[i][2] + bc, acc[i][3] + bc);
        float4 r1 = make_float4(acc[i][4] + bc, acc[i][5] + bc,
                                acc[i][6] + bc, acc[i][7] + bc);
        *(float4*)(out + ((size_t)b * 768 + row) * 1024 + t0 + tx * 4) = r0;
        *(float4*)(out + ((size_t)b * 768 + row) * 1024 + t0 + 64 + tx * 4) = r1;
    }
}

extern "C" void kernel_launch(void* const* d_in, const int* in_sizes, int n_in,
                              void* d_out, int out_size, void* d_ws, size_t ws_size,
                              hipStream_t stream) {
    const float* x     = (const float*)d_in[0];
    const float* Wq    = (const float*)d_in[1];
    const float* bq    = (const float*)d_in[2];
    const float* Wk    = (const float*)d_in[3];
    const float* bk    = (const float*)d_in[4];
    const float* Wv    = (const float*)d_in[5];
    const float* bv    = (const float*)d_in[6];
    const float* Wo    = (const float*)d_in[7];
    const float* bo    = (const float*)d_in[8];
    const float* Wg    = (const float*)d_in[9];
    const float* bg    = (const float*)d_in[10];
    const float* gamma = (const float*)d_in[11];
    const float* beta  = (const float*)d_in[12];
    float* out = (float*)d_out;

    // workspace layout (fp32): xn | q | k | v | g   (y overwrites xn)
    const size_t S = (size_t)BT_ * C_;
    float* xn = (float*)d_ws;
    float* q  = xn + S;
    float* k  = q + S;
    float* v  = k + S;
    float* g  = v + S;

    ln_kernel<<<BT_, 256, 0, stream>>>(x, gamma, beta, xn);
    qkvg_kernel<<<dim3(64, 24), 256, 0, stream>>>(xn, Wq, bq, Wk, bk, Wv, bv,
                                                  Wg, bg, q, k, v, g);
    attn_kernel<<<dim3(16, 12, 8), 256, 0, stream>>>(q, k, v, g, xn);  // y -> xn
    out_kernel<<<dim3(6, 64), 256, 0, stream>>>(xn, Wo, bo, out);
}

// Round 3
// 804.516 us; speedup vs baseline: 1.6408x; 1.5018x over previous
//
#include <hip/hip_runtime.h>
#include <math.h>

#define B_   8
#define C_   768
#define T_   1024
#define NH_  12
#define DH_  64
#define BT_  (B_*T_)       // 8192
#define WSZ  (C_*C_)       // 589824 per weight matrix

using bf16x8 = __attribute__((ext_vector_type(8))) short;
using f32x4  = __attribute__((ext_vector_type(4))) float;

// ---- bf16 split helpers (round-to-nearest-even) ----
__device__ inline unsigned short bf16_hi(float x) {
    unsigned u = __builtin_bit_cast(unsigned, x);
    u = (u + 0x7fffu + ((u >> 16) & 1u)) >> 16;
    return (unsigned short)u;
}
__device__ inline float bf16_f(unsigned short h) {
    unsigned u = ((unsigned)h) << 16;
    return __builtin_bit_cast(float, u);
}
__device__ inline void split_bf16(float x, unsigned short& h, unsigned short& l) {
    h = bf16_hi(x);
    l = bf16_hi(x - bf16_f(h));
}

// ---------------------------------------------------------------------------
// Kernel 0: weight fp32 -> bf16 hi/lo split (one matrix per launch)
// ---------------------------------------------------------------------------
__global__ __launch_bounds__(256) void wconv_kernel(const float* __restrict__ W,
                                                    unsigned short* __restrict__ hi,
                                                    unsigned short* __restrict__ lo) {
    int i = (blockIdx.x * 256 + threadIdx.x) * 4;
    float4 w = *(const float4*)(W + i);
    ushort4 h, l;
    split_bf16(w.x, h.x, l.x);
    split_bf16(w.y, h.y, l.y);
    split_bf16(w.z, h.z, l.z);
    split_bf16(w.w, h.w, l.w);
    *(ushort4*)(hi + i) = h;
    *(ushort4*)(lo + i) = l;
}

// ---------------------------------------------------------------------------
// Kernel 1: LayerNorm with (B,C,T)->(B*T,C) transpose; writes bf16 hi/lo.
// ---------------------------------------------------------------------------
__global__ __launch_bounds__(256) void ln_kernel(const float* __restrict__ x,
                                                 const float* __restrict__ gamma,
                                                 const float* __restrict__ beta,
                                                 unsigned short* __restrict__ xh,
                                                 unsigned short* __restrict__ xl) {
    int row = blockIdx.x;
    int b = row >> 10;
    int t = row & 1023;
    int tid = threadIdx.x;
    const float* xb = x + (size_t)b * C_ * T_ + t;
    float v0 = xb[(size_t)(tid      ) * T_];
    float v1 = xb[(size_t)(tid + 256) * T_];
    float v2 = xb[(size_t)(tid + 512) * T_];
    float s  = v0 + v1 + v2;
    float sq = v0 * v0 + v1 * v1 + v2 * v2;
    #pragma unroll
    for (int m = 1; m < 64; m <<= 1) {
        s  += __shfl_xor(s,  m);
        sq += __shfl_xor(sq, m);
    }
    __shared__ float ss[4], ssq[4];
    int wid = tid >> 6;
    if ((tid & 63) == 0) { ss[wid] = s; ssq[wid] = sq; }
    __syncthreads();
    s  = ss[0] + ss[1] + ss[2] + ss[3];
    sq = ssq[0] + ssq[1] + ssq[2] + ssq[3];
    float mu   = s * (1.0f / 768.0f);
    float var  = sq * (1.0f / 768.0f) - mu * mu;
    float rstd = 1.0f / sqrtf(var + 1e-5f);
    size_t o = (size_t)row * C_;
    float r0 = (v0 - mu) * rstd * gamma[tid      ] + beta[tid      ];
    float r1 = (v1 - mu) * rstd * gamma[tid + 256] + beta[tid + 256];
    float r2 = (v2 - mu) * rstd * gamma[tid + 512] + beta[tid + 512];
    unsigned short h, l;
    split_bf16(r0, h, l); xh[o + tid      ] = h; xl[o + tid      ] = l;
    split_bf16(r1, h, l); xh[o + tid + 256] = h; xl[o + tid + 256] = l;
    split_bf16(r2, h, l); xh[o + tid + 512] = h; xl[o + tid + 512] = l;
}

// ---------------------------------------------------------------------------
// Kernel 2: fused QKVG GEMM, split-bf16 MFMA (D = Ah*Bh + Ah*Bl + Al*Bh).
// Block 128x128, 4 waves (2x2) of 64x64, 16x16x32 bf16 MFMA, BK=32.
// LDS rows padded to 40 bf16 (80 B): fragment b128 reads 2-way (free).
// q,k,v stored fp32; gate stored bf16 (pre-sigmoid).
// ---------------------------------------------------------------------------
__global__ __launch_bounds__(256, 2) void qkvg_mfma(
    const unsigned short* __restrict__ xh, const unsigned short* __restrict__ xl,
    const unsigned short* __restrict__ wmats,
    const float* __restrict__ bq, const float* __restrict__ bk,
    const float* __restrict__ bv, const float* __restrict__ bg,
    float* __restrict__ q, float* __restrict__ k, float* __restrict__ v,
    unsigned short* __restrict__ g) {
    int bx = blockIdx.x;            // m tile 0..63
    int by = blockIdx.y;            // 0..23
    int mat = by / 6;
    int n0  = (by % 6) * 128;
    int m0  = bx * 128;
    const unsigned short* Wh = wmats + (size_t)mat * 2 * WSZ;
    const unsigned short* Wl = Wh + WSZ;
    const float* bias = (mat == 0) ? bq : (mat == 1) ? bk : (mat == 2) ? bv : bg;

    __shared__ unsigned short Ah[128][40], Al[128][40];
    __shared__ unsigned short Bh[128][40], Bl[128][40];

    int tid  = threadIdx.x;
    int lane = tid & 63, wid = tid >> 6;
    int wm = (wid & 1) * 64, wn = (wid >> 1) * 64;
    int fr = lane & 15, fq = (lane >> 4) * 8;

    f32x4 acc[4][4];
    #pragma unroll
    for (int i = 0; i < 4; ++i)
        #pragma unroll
        for (int j = 0; j < 4; ++j)
            acc[i][j] = (f32x4){0.f, 0.f, 0.f, 0.f};

    int sr = tid >> 1;              // 0..127 staging row
    int sc = (tid & 1) * 16;        // 0 / 16 (ushort offset within 32-col window)
    const unsigned short* pAh = xh + (size_t)(m0 + sr) * 768 + sc;
    const unsigned short* pAl = xl + (size_t)(m0 + sr) * 768 + sc;
    const unsigned short* pBh = Wh + (size_t)(n0 + sr) * 768 + sc;
    const unsigned short* pBl = Wl + (size_t)(n0 + sr) * 768 + sc;

    for (int k0 = 0; k0 < 768; k0 += 32) {
        uint4 a0 = *(const uint4*)(pAh + k0);
        uint4 a1 = *(const uint4*)(pAh + k0 + 8);
        uint4 b0 = *(const uint4*)(pAl + k0);
        uint4 b1 = *(const uint4*)(pAl + k0 + 8);
        uint4 c0 = *(const uint4*)(pBh + k0);
        uint4 c1 = *(const uint4*)(pBh + k0 + 8);
        uint4 d0 = *(const uint4*)(pBl + k0);
        uint4 d1 = *(const uint4*)(pBl + k0 + 8);
        *(uint4*)&Ah[sr][sc]     = a0;
        *(uint4*)&Ah[sr][sc + 8] = a1;
        *(uint4*)&Al[sr][sc]     = b0;
        *(uint4*)&Al[sr][sc + 8] = b1;
        *(uint4*)&Bh[sr][sc]     = c0;
        *(uint4*)&Bh[sr][sc + 8] = c1;
        *(uint4*)&Bl[sr][sc]     = d0;
        *(uint4*)&Bl[sr][sc + 8] = d1;
        __syncthreads();
        bf16x8 ah[4], al[4], bh[4], bl[4];
        #pragma unroll
        for (int i = 0; i < 4; ++i) {
            ah[i] = *(const bf16x8*)&Ah[wm + i * 16 + fr][fq];
            al[i] = *(const bf16x8*)&Al[wm + i * 16 + fr][fq];
            bh[i] = *(const bf16x8*)&Bh[wn + i * 16 + fr][fq];
            bl[i] = *(const bf16x8*)&Bl[wn + i * 16 + fr][fq];
        }
        #pragma unroll
        for (int mi = 0; mi < 4; ++mi)
            #pragma unroll
            for (int ni = 0; ni < 4; ++ni) {
                acc[mi][ni] = __builtin_amdgcn_mfma_f32_16x16x32_bf16(ah[mi], bh[ni], acc[mi][ni], 0, 0, 0);
                acc[mi][ni] = __builtin_amdgcn_mfma_f32_16x16x32_bf16(ah[mi], bl[ni], acc[mi][ni], 0, 0, 0);
                acc[mi][ni] = __builtin_amdgcn_mfma_f32_16x16x32_bf16(al[mi], bh[ni], acc[mi][ni], 0, 0, 0);
            }
        __syncthreads();
    }
    // epilogue: C/D layout col=lane&15, row=(lane>>4)*4+reg
    int rq = (lane >> 4) * 4;
    float* outp = (mat == 0) ? q : (mat == 1) ? k : v;
    #pragma unroll
    for (int ni = 0; ni < 4; ++ni) {
        int col = n0 + wn + ni * 16 + fr;
        float bb = bias[col];
        #pragma unroll
        for (int mi = 0; mi < 4; ++mi) {
            int row = m0 + wm + mi * 16 + rq;
            #pragma unroll
            for (int rg = 0; rg < 4; ++rg) {
                float val = acc[mi][ni][rg] + bb;
                if (mat < 3) outp[(size_t)(row + rg) * 768 + col] = val;
                else         g[(size_t)(row + rg) * 768 + col] = bf16_hi(val);
            }
        }
    }
}

// ---------------------------------------------------------------------------
// Kernel 3: flash-style attention + bf16 sigmoid gate; writes y as bf16 hi/lo.
// ---------------------------------------------------------------------------
__global__ __launch_bounds__(256) void attn_kernel(
    const float* __restrict__ q, const float* __restrict__ k,
    const float* __restrict__ v, const unsigned short* __restrict__ g,
    unsigned short* __restrict__ yh, unsigned short* __restrict__ yl) {
    int qt = blockIdx.x;
    int h  = blockIdx.y;
    int b  = blockIdx.z;
    __shared__ float Qs[64][68];
    __shared__ float KVs[64][68];
    __shared__ float Ps[64][68];
    int tid = threadIdx.x;
    int tx = tid & 15, ty = tid >> 4;
    size_t headoff = (size_t)h * 64;
    const float* qg = q + (size_t)(b * 1024 + qt * 64) * 768 + headoff;
    #pragma unroll
    for (int it = 0; it < 4; ++it) {
        int idx = tid + it * 256;
        int r = idx >> 4, c4 = (idx & 15) * 4;
        float4 qv = *(const float4*)(qg + (size_t)r * 768 + c4);
        qv.x *= 0.125f; qv.y *= 0.125f; qv.z *= 0.125f; qv.w *= 0.125f;
        *(float4*)&Qs[r][c4] = qv;
    }
    float m_i[4], l_i[4], Oacc[4][4] = {};
    #pragma unroll
    for (int i = 0; i < 4; ++i) { m_i[i] = -1e30f; l_i[i] = 0.0f; }
    const float* kg = k + (size_t)(b * 1024) * 768 + headoff;
    const float* vg = v + (size_t)(b * 1024) * 768 + headoff;

    for (int st = 0; st < 16; ++st) {
        #pragma unroll
        for (int it = 0; it < 4; ++it) {
            int idx = tid + it * 256;
            int r = idx >> 4, c4 = (idx & 15) * 4;
            *(float4*)&KVs[r][c4] =
                *(const float4*)(kg + (size_t)(st * 64 + r) * 768 + c4);
        }
        __syncthreads();
        float sacc[4][4] = {};
        #pragma unroll
        for (int d0 = 0; d0 < 64; d0 += 4) {
            float4 qa[4], kb[4];
            #pragma unroll
            for (int i = 0; i < 4; ++i) qa[i] = *(const float4*)&Qs[ty * 4 + i][d0];
            #pragma unroll
            for (int j = 0; j < 4; ++j) kb[j] = *(const float4*)&KVs[j * 16 + tx][d0];
            #pragma unroll
            for (int i = 0; i < 4; ++i)
                #pragma unroll
                for (int j = 0; j < 4; ++j)
                    sacc[i][j] += qa[i].x * kb[j].x + qa[i].y * kb[j].y +
                                  qa[i].z * kb[j].z + qa[i].w * kb[j].w;
        }
        #pragma unroll
        for (int i = 0; i < 4; ++i) {
            float mx = fmaxf(fmaxf(sacc[i][0], sacc[i][1]),
                             fmaxf(sacc[i][2], sacc[i][3]));
            #pragma unroll
            for (int msk = 1; msk < 16; msk <<= 1) mx = fmaxf(mx, __shfl_xor(mx, msk));
            float m_new = fmaxf(m_i[i], mx);
            float alpha = __expf(m_i[i] - m_new);
            float p0 = __expf(sacc[i][0] - m_new);
            float p1 = __expf(sacc[i][1] - m_new);
            float p2 = __expf(sacc[i][2] - m_new);
            float p3 = __expf(sacc[i][3] - m_new);
            float rs = p0 + p1 + p2 + p3;
            #pragma unroll
            for (int msk = 1; msk < 16; msk <<= 1) rs += __shfl_xor(rs, msk);
            l_i[i] = l_i[i] * alpha + rs;
            m_i[i] = m_new;
            #pragma unroll
            for (int j = 0; j < 4; ++j) Oacc[i][j] *= alpha;
            Ps[ty * 4 + i][ 0 + tx] = p0;
            Ps[ty * 4 + i][16 + tx] = p1;
            Ps[ty * 4 + i][32 + tx] = p2;
            Ps[ty * 4 + i][48 + tx] = p3;
        }
        __syncthreads();
        #pragma unroll
        for (int it = 0; it < 4; ++it) {
            int idx = tid + it * 256;
            int r = idx >> 4, c4 = (idx & 15) * 4;
            *(float4*)&KVs[r][c4] =
                *(const float4*)(vg + (size_t)(st * 64 + r) * 768 + c4);
        }
        __syncthreads();
        #pragma unroll
        for (int s0 = 0; s0 < 64; s0 += 4) {
            float4 pa[4], vb[4];
            #pragma unroll
            for (int i = 0; i < 4; ++i) pa[i] = *(const float4*)&Ps[ty * 4 + i][s0];
            #pragma unroll
            for (int ss = 0; ss < 4; ++ss) vb[ss] = *(const float4*)&KVs[s0 + ss][tx * 4];
            #pragma unroll
            for (int i = 0; i < 4; ++i) {
                float pv[4] = {pa[i].x, pa[i].y, pa[i].z, pa[i].w};
                #pragma unroll
                for (int ss = 0; ss < 4; ++ss) {
                    Oacc[i][0] = fmaf(pv[ss], vb[ss].x, Oacc[i][0]);
                    Oacc[i][1] = fmaf(pv[ss], vb[ss].y, Oacc[i][1]);
                    Oacc[i][2] = fmaf(pv[ss], vb[ss].z, Oacc[i][2]);
                    Oacc[i][3] = fmaf(pv[ss], vb[ss].w, Oacc[i][3]);
                }
            }
        }
        __syncthreads();
    }
    const unsigned short* gg = g + (size_t)(b * 1024 + qt * 64) * 768 + headoff;
    unsigned short* yho = yh + (size_t)(b * 1024 + qt * 64) * 768 + headoff;
    unsigned short* ylo = yl + (size_t)(b * 1024 + qt * 64) * 768 + headoff;
    #pragma unroll
    for (int i = 0; i < 4; ++i) {
        float inv = 1.0f / l_i[i];
        ushort4 gu = *(const ushort4*)(gg + (size_t)(ty * 4 + i) * 768 + tx * 4);
        float r0 = Oacc[i][0] * inv * (1.0f / (1.0f + __expf(-bf16_f(gu.x))));
        float r1 = Oacc[i][1] * inv * (1.0f / (1.0f + __expf(-bf16_f(gu.y))));
        float r2 = Oacc[i][2] * inv * (1.0f / (1.0f + __expf(-bf16_f(gu.z))));
        float r3 = Oacc[i][3] * inv * (1.0f / (1.0f + __expf(-bf16_f(gu.w))));
        ushort4 h4, l4;
        split_bf16(r0, h4.x, l4.x);
        split_bf16(r1, h4.y, l4.y);
        split_bf16(r2, h4.z, l4.z);
        split_bf16(r3, h4.w, l4.w);
        *(ushort4*)(yho + (size_t)(ty * 4 + i) * 768 + tx * 4) = h4;
        *(ushort4*)(ylo + (size_t)(ty * 4 + i) * 768 + tx * 4) = l4;
    }
}

// ---------------------------------------------------------------------------
// Kernel 4: out = y @ Wo^T + bo -> (B, C, T), split-bf16 MFMA.
// M-dim = c (768, 6 tiles), N-dim = t (8192, 64 tiles): stores contiguous in t.
// ---------------------------------------------------------------------------
__global__ __launch_bounds__(256, 2) void out_mfma(
    const unsigned short* __restrict__ yh, const unsigned short* __restrict__ yl,
    const unsigned short* __restrict__ woh, const unsigned short* __restrict__ wol,
    const float* __restrict__ bo, float* __restrict__ out) {
    int bx = blockIdx.x;   // c tile 0..5
    int by = blockIdx.y;   // t tile 0..63
    int m0 = bx * 128;     // c
    int n0 = by * 128;     // t (global row index of y)

    __shared__ unsigned short Ah[128][40], Al[128][40];
    __shared__ unsigned short Bh[128][40], Bl[128][40];

    int tid  = threadIdx.x;
    int lane = tid & 63, wid = tid >> 6;
    int wm = (wid & 1) * 64, wn = (wid >> 1) * 64;
    int fr = lane & 15, fq = (lane >> 4) * 8;

    f32x4 acc[4][4];
    #pragma unroll
    for (int i = 0; i < 4; ++i)
        #pragma unroll
        for (int j = 0; j < 4; ++j)
            acc[i][j] = (f32x4){0.f, 0.f, 0.f, 0.f};

    int sr = tid >> 1;
    int sc = (tid & 1) * 16;
    const unsigned short* pAh = woh + (size_t)(m0 + sr) * 768 + sc;
    const unsigned short* pAl = wol + (size_t)(m0 + sr) * 768 + sc;
    const unsigned short* pBh = yh  + (size_t)(n0 + sr) * 768 + sc;
    const unsigned short* pBl = yl  + (size_t)(n0 + sr) * 768 + sc;

    for (int k0 = 0; k0 < 768; k0 += 32) {
        uint4 a0 = *(const uint4*)(pAh + k0);
        uint4 a1 = *(const uint4*)(pAh + k0 + 8);
        uint4 b0 = *(const uint4*)(pAl + k0);
        uint4 b1 = *(const uint4*)(pAl + k0 + 8);
        uint4 c0 = *(const uint4*)(pBh + k0);
        uint4 c1 = *(const uint4*)(pBh + k0 + 8);
        uint4 d0 = *(const uint4*)(pBl + k0);
        uint4 d1 = *(const uint4*)(pBl + k0 + 8);
        *(uint4*)&Ah[sr][sc]     = a0;
        *(uint4*)&Ah[sr][sc + 8] = a1;
        *(uint4*)&Al[sr][sc]     = b0;
        *(uint4*)&Al[sr][sc + 8] = b1;
        *(uint4*)&Bh[sr][sc]     = c0;
        *(uint4*)&Bh[sr][sc + 8] = c1;
        *(uint4*)&Bl[sr][sc]     = d0;
        *(uint4*)&Bl[sr][sc + 8] = d1;
        __syncthreads();
        bf16x8 ah[4], al[4], bh[4], bl[4];
        #pragma unroll
        for (int i = 0; i < 4; ++i) {
            ah[i] = *(const bf16x8*)&Ah[wm + i * 16 + fr][fq];
            al[i] = *(const bf16x8*)&Al[wm + i * 16 + fr][fq];
            bh[i] = *(const bf16x8*)&Bh[wn + i * 16 + fr][fq];
            bl[i] = *(const bf16x8*)&Bl[wn + i * 16 + fr][fq];
        }
        #pragma unroll
        for (int mi = 0; mi < 4; ++mi)
            #pragma unroll
            for (int ni = 0; ni < 4; ++ni) {
                acc[mi][ni] = __builtin_amdgcn_mfma_f32_16x16x32_bf16(ah[mi], bh[ni], acc[mi][ni], 0, 0, 0);
                acc[mi][ni] = __builtin_amdgcn_mfma_f32_16x16x32_bf16(ah[mi], bl[ni], acc[mi][ni], 0, 0, 0);
                acc[mi][ni] = __builtin_amdgcn_mfma_f32_16x16x32_bf16(al[mi], bh[ni], acc[mi][ni], 0, 0, 0);
            }
        __syncthreads();
    }
    int rq = (lane >> 4) * 4;
    int bb = n0 >> 10;                 // batch (uniform per block: 128 | 1024)
    #pragma unroll
    for (int ni = 0; ni < 4; ++ni) {
        int colg = n0 + wn + ni * 16 + fr;   // global t index
        int tl = colg & 1023;
        #pragma unroll
        for (int mi = 0; mi < 4; ++mi) {
            int row = m0 + wm + mi * 16 + rq;  // c index
            #pragma unroll
            for (int rg = 0; rg < 4; ++rg) {
                float val = acc[mi][ni][rg] + bo[row + rg];
                out[((size_t)bb * 768 + row + rg) * 1024 + tl] = val;
            }
        }
    }
}

extern "C" void kernel_launch(void* const* d_in, const int* in_sizes, int n_in,
                              void* d_out, int out_size, void* d_ws, size_t ws_size,
                              hipStream_t stream) {
    const float* x     = (const float*)d_in[0];
    const float* Wq    = (const float*)d_in[1];
    const float* bq    = (const float*)d_in[2];
    const float* Wk    = (const float*)d_in[3];
    const float* bk    = (const float*)d_in[4];
    const float* Wv    = (const float*)d_in[5];
    const float* bv    = (const float*)d_in[6];
    const float* Wo    = (const float*)d_in[7];
    const float* bo    = (const float*)d_in[8];
    const float* Wg    = (const float*)d_in[9];
    const float* bg    = (const float*)d_in[10];
    const float* gamma = (const float*)d_in[11];
    const float* beta  = (const float*)d_in[12];
    float* out = (float*)d_out;

    // workspace: xn_hi | xn_lo | q | k | v | g_bf16 | 10x W-split  (125 MB)
    const size_t S = (size_t)BT_ * C_;
    unsigned short* xn_hi = (unsigned short*)d_ws;
    unsigned short* xn_lo = xn_hi + S;
    float* q = (float*)(xn_lo + S);
    float* k = q + S;
    float* v = k + S;
    unsigned short* g_bf = (unsigned short*)(v + S);
    unsigned short* wbuf = g_bf + S;   // [Wq,Wk,Wv,Wg,Wo] x {hi,lo}, WSZ each
    unsigned short* y_hi = xn_hi;      // alias: xn dead after qkvg
    unsigned short* y_lo = xn_lo;

    const float* wsrc[5] = {Wq, Wk, Wv, Wg, Wo};
    for (int i = 0; i < 5; ++i)
        wconv_kernel<<<WSZ / 1024, 256, 0, stream>>>(
            wsrc[i], wbuf + (size_t)i * 2 * WSZ, wbuf + (size_t)(i * 2 + 1) * WSZ);

    ln_kernel<<<BT_, 256, 0, stream>>>(x, gamma, beta, xn_hi, xn_lo);
    qkvg_mfma<<<dim3(64, 24), 256, 0, stream>>>(xn_hi, xn_lo, wbuf,
                                                bq, bk, bv, bg, q, k, v, g_bf);
    attn_kernel<<<dim3(16, 12, 8), 256, 0, stream>>>(q, k, v, g_bf, y_hi, y_lo);
    out_mfma<<<dim3(6, 64), 256, 0, stream>>>(y_hi, y_lo,
                                              wbuf + (size_t)8 * WSZ,
                                              wbuf + (size_t)9 * WSZ, bo, out);
}

// Round 4
// 447.554 us; speedup vs baseline: 2.9494x; 1.7976x over previous
//
#include <hip/hip_runtime.h>
#include <math.h>

#define B_   8
#define C_   768
#define T_   1024
#define NH_  12
#define DH_  64
#define BT_  (B_*T_)       // 8192
#define WSZ  (C_*C_)       // 589824 per weight matrix

using bf16x8 = __attribute__((ext_vector_type(8))) short;
using f32x4  = __attribute__((ext_vector_type(4))) float;
typedef unsigned short ushort_t;

// ---- bf16 split helpers (round-to-nearest-even) ----
__device__ inline unsigned short bf16_hi(float x) {
    unsigned u = __builtin_bit_cast(unsigned, x);
    u = (u + 0x7fffu + ((u >> 16) & 1u)) >> 16;
    return (unsigned short)u;
}
__device__ inline float bf16_f(unsigned short h) {
    unsigned u = ((unsigned)h) << 16;
    return __builtin_bit_cast(float, u);
}
__device__ inline void split_bf16(float x, unsigned short& h, unsigned short& l) {
    h = bf16_hi(x);
    l = bf16_hi(x - bf16_f(h));
}

// ---------------------------------------------------------------------------
// Kernel 0: weight fp32 -> bf16 hi/lo split
// ---------------------------------------------------------------------------
__global__ __launch_bounds__(256) void wconv_kernel(const float* __restrict__ W,
                                                    unsigned short* __restrict__ hi,
                                                    unsigned short* __restrict__ lo) {
    int i = (blockIdx.x * 256 + threadIdx.x) * 4;
    float4 w = *(const float4*)(W + i);
    ushort4 h, l;
    split_bf16(w.x, h.x, l.x);
    split_bf16(w.y, h.y, l.y);
    split_bf16(w.z, h.z, l.z);
    split_bf16(w.w, h.w, l.w);
    *(ushort4*)(hi + i) = h;
    *(ushort4*)(lo + i) = l;
}

// ---------------------------------------------------------------------------
// Kernel 1: LayerNorm with (B,C,T)->(B*T,C) transpose; writes bf16 hi/lo.
// ---------------------------------------------------------------------------
__global__ __launch_bounds__(256) void ln_kernel(const float* __restrict__ x,
                                                 const float* __restrict__ gamma,
                                                 const float* __restrict__ beta,
                                                 unsigned short* __restrict__ xh,
                                                 unsigned short* __restrict__ xl) {
    int row = blockIdx.x;
    int b = row >> 10;
    int t = row & 1023;
    int tid = threadIdx.x;
    const float* xb = x + (size_t)b * C_ * T_ + t;
    float v0 = xb[(size_t)(tid      ) * T_];
    float v1 = xb[(size_t)(tid + 256) * T_];
    float v2 = xb[(size_t)(tid + 512) * T_];
    float s  = v0 + v1 + v2;
    float sq = v0 * v0 + v1 * v1 + v2 * v2;
    #pragma unroll
    for (int m = 1; m < 64; m <<= 1) {
        s  += __shfl_xor(s,  m);
        sq += __shfl_xor(sq, m);
    }
    __shared__ float ss[4], ssq[4];
    int wid = tid >> 6;
    if ((tid & 63) == 0) { ss[wid] = s; ssq[wid] = sq; }
    __syncthreads();
    s  = ss[0] + ss[1] + ss[2] + ss[3];
    sq = ssq[0] + ssq[1] + ssq[2] + ssq[3];
    float mu   = s * (1.0f / 768.0f);
    float var  = sq * (1.0f / 768.0f) - mu * mu;
    float rstd = 1.0f / sqrtf(var + 1e-5f);
    size_t o = (size_t)row * C_;
    float r0 = (v0 - mu) * rstd * gamma[tid      ] + beta[tid      ];
    float r1 = (v1 - mu) * rstd * gamma[tid + 256] + beta[tid + 256];
    float r2 = (v2 - mu) * rstd * gamma[tid + 512] + beta[tid + 512];
    unsigned short h, l;
    split_bf16(r0, h, l); xh[o + tid      ] = h; xl[o + tid      ] = l;
    split_bf16(r1, h, l); xh[o + tid + 256] = h; xl[o + tid + 256] = l;
    split_bf16(r2, h, l); xh[o + tid + 512] = h; xl[o + tid + 512] = l;
}

// ---------------------------------------------------------------------------
// Kernel 2: fused QKVG GEMM, split-bf16 MFMA.
// mat 0 (Q): writes bf16 hi/lo, pre-scaled by 1/sqrt(64), token-major.
// mat 1 (K): writes bf16 hi/lo token-major.
// mat 2 (V): MFMA operands SWAPPED -> D = W.X^T: epilogue emits V^T in
//            [b][h][d][t] layout (bf16 hi/lo) -- no transpose kernel needed.
// mat 3 (G): bf16 pre-sigmoid gate.
// ---------------------------------------------------------------------------
__global__ __launch_bounds__(256, 2) void qkvg_mfma(
    const unsigned short* __restrict__ xh, const unsigned short* __restrict__ xl,
    const unsigned short* __restrict__ wmats,
    const float* __restrict__ bq, const float* __restrict__ bk,
    const float* __restrict__ bv, const float* __restrict__ bg,
    unsigned short* __restrict__ qh, unsigned short* __restrict__ ql,
    unsigned short* __restrict__ kh, unsigned short* __restrict__ kl,
    unsigned short* __restrict__ vth, unsigned short* __restrict__ vtl,
    unsigned short* __restrict__ g) {
    int bx = blockIdx.x;            // m tile 0..63
    int by = blockIdx.y;            // 0..23
    int mat = by / 6;
    int n0  = (by % 6) * 128;
    int m0  = bx * 128;
    const unsigned short* Wh = wmats + (size_t)mat * 2 * WSZ;
    const unsigned short* Wl = Wh + WSZ;
    const float* bias = (mat == 0) ? bq : (mat == 1) ? bk : (mat == 2) ? bv : bg;

    __shared__ unsigned short Ah[128][40], Al[128][40];
    __shared__ unsigned short Bh[128][40], Bl[128][40];

    int tid  = threadIdx.x;
    int lane = tid & 63, wid = tid >> 6;
    int wm = (wid & 1) * 64, wn = (wid >> 1) * 64;
    int fr = lane & 15, fq = (lane >> 4) * 8;

    f32x4 acc[4][4];
    #pragma unroll
    for (int i = 0; i < 4; ++i)
        #pragma unroll
        for (int j = 0; j < 4; ++j)
            acc[i][j] = (f32x4){0.f, 0.f, 0.f, 0.f};

    int sr = tid >> 1;
    int sc = (tid & 1) * 16;
    const unsigned short* pAh = xh + (size_t)(m0 + sr) * 768 + sc;
    const unsigned short* pAl = xl + (size_t)(m0 + sr) * 768 + sc;
    const unsigned short* pBh = Wh + (size_t)(n0 + sr) * 768 + sc;
    const unsigned short* pBl = Wl + (size_t)(n0 + sr) * 768 + sc;

    for (int k0 = 0; k0 < 768; k0 += 32) {
        uint4 a0 = *(const uint4*)(pAh + k0);
        uint4 a1 = *(const uint4*)(pAh + k0 + 8);
        uint4 b0 = *(const uint4*)(pAl + k0);
        uint4 b1 = *(const uint4*)(pAl + k0 + 8);
        uint4 c0 = *(const uint4*)(pBh + k0);
        uint4 c1 = *(const uint4*)(pBh + k0 + 8);
        uint4 d0 = *(const uint4*)(pBl + k0);
        uint4 d1 = *(const uint4*)(pBl + k0 + 8);
        *(uint4*)&Ah[sr][sc]     = a0;
        *(uint4*)&Ah[sr][sc + 8] = a1;
        *(uint4*)&Al[sr][sc]     = b0;
        *(uint4*)&Al[sr][sc + 8] = b1;
        *(uint4*)&Bh[sr][sc]     = c0;
        *(uint4*)&Bh[sr][sc + 8] = c1;
        *(uint4*)&Bl[sr][sc]     = d0;
        *(uint4*)&Bl[sr][sc + 8] = d1;
        __syncthreads();
        bf16x8 ah[4], al[4], bh[4], bl[4];
        #pragma unroll
        for (int i = 0; i < 4; ++i) {
            ah[i] = *(const bf16x8*)&Ah[wm + i * 16 + fr][fq];
            al[i] = *(const bf16x8*)&Al[wm + i * 16 + fr][fq];
            bh[i] = *(const bf16x8*)&Bh[wn + i * 16 + fr][fq];
            bl[i] = *(const bf16x8*)&Bl[wn + i * 16 + fr][fq];
        }
        if (mat == 2) {
            #pragma unroll
            for (int mi = 0; mi < 4; ++mi)
                #pragma unroll
                for (int ni = 0; ni < 4; ++ni) {
                    acc[mi][ni] = __builtin_amdgcn_mfma_f32_16x16x32_bf16(bh[ni], ah[mi], acc[mi][ni], 0, 0, 0);
                    acc[mi][ni] = __builtin_amdgcn_mfma_f32_16x16x32_bf16(bh[ni], al[mi], acc[mi][ni], 0, 0, 0);
                    acc[mi][ni] = __builtin_amdgcn_mfma_f32_16x16x32_bf16(bl[ni], ah[mi], acc[mi][ni], 0, 0, 0);
                }
        } else {
            #pragma unroll
            for (int mi = 0; mi < 4; ++mi)
                #pragma unroll
                for (int ni = 0; ni < 4; ++ni) {
                    acc[mi][ni] = __builtin_amdgcn_mfma_f32_16x16x32_bf16(ah[mi], bh[ni], acc[mi][ni], 0, 0, 0);
                    acc[mi][ni] = __builtin_amdgcn_mfma_f32_16x16x32_bf16(ah[mi], bl[ni], acc[mi][ni], 0, 0, 0);
                    acc[mi][ni] = __builtin_amdgcn_mfma_f32_16x16x32_bf16(al[mi], bh[ni], acc[mi][ni], 0, 0, 0);
                }
        }
        __syncthreads();
    }
    int rq = (lane >> 4) * 4;
    if (mat == 2) {
        // D rows = channel (n0-space), cols = token (m0-space)
        int bb = m0 >> 10;
        #pragma unroll
        for (int mi = 0; mi < 4; ++mi) {
            int tok = m0 + wm + mi * 16 + fr;
            int tl  = tok & 1023;
            #pragma unroll
            for (int ni = 0; ni < 4; ++ni) {
                #pragma unroll
                for (int rg = 0; rg < 4; ++rg) {
                    int ch = n0 + wn + ni * 16 + rq + rg;
                    float val = acc[mi][ni][rg] + bias[ch];
                    int hh = ch >> 6, dd = ch & 63;
                    size_t addr = ((size_t)((bb * 12 + hh) * 64 + dd)) * 1024 + tl;
                    unsigned short h, l;
                    split_bf16(val, h, l);
                    vth[addr] = h;
                    vtl[addr] = l;
                }
            }
        }
    } else {
        unsigned short* oh = (mat == 0) ? qh : (mat == 1) ? kh : g;
        unsigned short* ol = (mat == 0) ? ql : kl;
        #pragma unroll
        for (int ni = 0; ni < 4; ++ni) {
            int col = n0 + wn + ni * 16 + fr;
            float bb = bias[col];
            #pragma unroll
            for (int mi = 0; mi < 4; ++mi) {
                int row = m0 + wm + mi * 16 + rq;
                #pragma unroll
                for (int rg = 0; rg < 4; ++rg) {
                    float val = acc[mi][ni][rg] + bb;
                    size_t addr = (size_t)(row + rg) * 768 + col;
                    if (mat == 3) {
                        g[addr] = bf16_hi(val);
                    } else {
                        if (mat == 0) val *= 0.125f;   // fold 1/sqrt(64)
                        unsigned short h, l;
                        split_bf16(val, h, l);
                        oh[addr] = h;
                        ol[addr] = l;
                    }
                }
            }
        }
    }
}

// ---------------------------------------------------------------------------
// Kernel 3: MFMA flash attention + bf16 sigmoid gate.
// Block = 64 q-rows (qt), 4 waves x 16-row strips; wave-local online softmax.
// QK^T: split Q x split K (3 MFMA); P: plain bf16; PV: P x split V (2 MFMA).
// K/V share one LDS buffer pair; V arrives pre-transposed ([b,h,d,t]).
// LDS = 5 x 64x72 ushort = 46 KB -> 3 blocks/CU.
// ---------------------------------------------------------------------------
__global__ __launch_bounds__(256, 3) void attn_mfma(
    const unsigned short* __restrict__ qhg, const unsigned short* __restrict__ qlg,
    const unsigned short* __restrict__ khg, const unsigned short* __restrict__ klg,
    const unsigned short* __restrict__ vthg, const unsigned short* __restrict__ vtlg,
    const unsigned short* __restrict__ gbf,
    unsigned short* __restrict__ yh, unsigned short* __restrict__ yl) {
    int qt = blockIdx.x;   // 0..15
    int h  = blockIdx.y;   // 0..11
    int b  = blockIdx.z;   // 0..7
    __shared__ unsigned short Qh[64][72], Ql[64][72];
    __shared__ unsigned short Kh[64][72], Kl[64][72];   // K tile, then V^T tile
    __shared__ unsigned short Ps[64][72];
    int tid = threadIdx.x;
    int lane = tid & 63, w = tid >> 6;
    int fr = lane & 15, quad = lane >> 4, fq = quad * 8;

    // stage Q (64 rows x 64 bf16, hi+lo)
    size_t qbase = ((size_t)(b * 1024 + qt * 64)) * 768 + h * 64;
    #pragma unroll
    for (int it = 0; it < 2; ++it) {
        int idx = tid + it * 256;          // 0..511
        int r = idx >> 3, c = (idx & 7) * 8;
        *(uint4*)&Qh[r][c] = *(const uint4*)(qhg + qbase + (size_t)r * 768 + c);
        *(uint4*)&Ql[r][c] = *(const uint4*)(qlg + qbase + (size_t)r * 768 + c);
    }
    float m_i[4], l_i[4];
    f32x4 Oacc[4];
    #pragma unroll
    for (int i = 0; i < 4; ++i) {
        m_i[i] = -1e30f; l_i[i] = 0.0f;
        Oacc[i] = (f32x4){0.f, 0.f, 0.f, 0.f};
    }
    size_t kbase = ((size_t)(b * 1024)) * 768 + h * 64;
    size_t vbase = ((size_t)((b * 12 + h) * 64)) * 1024;
    __syncthreads();
    // Q A-fragments are loop-invariant: preload
    bf16x8 aqh[2], aql[2];
    #pragma unroll
    for (int kk = 0; kk < 2; ++kk) {
        aqh[kk] = *(const bf16x8*)&Qh[w * 16 + fr][fq + kk * 32];
        aql[kk] = *(const bf16x8*)&Ql[w * 16 + fr][fq + kk * 32];
    }

    for (int st = 0; st < 16; ++st) {
        // stage K tile (rows = s, cols = d)
        #pragma unroll
        for (int it = 0; it < 2; ++it) {
            int idx = tid + it * 256;
            int r = idx >> 3, c = (idx & 7) * 8;
            *(uint4*)&Kh[r][c] = *(const uint4*)(khg + kbase + (size_t)(st * 64 + r) * 768 + c);
            *(uint4*)&Kl[r][c] = *(const uint4*)(klg + kbase + (size_t)(st * 64 + r) * 768 + c);
        }
        __syncthreads();
        // S = Q K^T (wave strip 16 x 64), 3-MFMA split
        f32x4 sacc[4];
        #pragma unroll
        for (int nt = 0; nt < 4; ++nt) sacc[nt] = (f32x4){0.f, 0.f, 0.f, 0.f};
        #pragma unroll
        for (int nt = 0; nt < 4; ++nt)
            #pragma unroll
            for (int kk = 0; kk < 2; ++kk) {
                bf16x8 kbh = *(const bf16x8*)&Kh[nt * 16 + fr][fq + kk * 32];
                bf16x8 kbl = *(const bf16x8*)&Kl[nt * 16 + fr][fq + kk * 32];
                sacc[nt] = __builtin_amdgcn_mfma_f32_16x16x32_bf16(aqh[kk], kbh, sacc[nt], 0, 0, 0);
                sacc[nt] = __builtin_amdgcn_mfma_f32_16x16x32_bf16(aqh[kk], kbl, sacc[nt], 0, 0, 0);
                sacc[nt] = __builtin_amdgcn_mfma_f32_16x16x32_bf16(aql[kk], kbh, sacc[nt], 0, 0, 0);
            }
        __syncthreads();   // all K-frag reads done before V overwrites buffer
        // online softmax per owned row (row = w*16 + quad*4 + rg)
        #pragma unroll
        for (int rg = 0; rg < 4; ++rg) {
            float mx = fmaxf(fmaxf(sacc[0][rg], sacc[1][rg]),
                             fmaxf(sacc[2][rg], sacc[3][rg]));
            #pragma unroll
            for (int msk = 1; msk < 16; msk <<= 1) mx = fmaxf(mx, __shfl_xor(mx, msk));
            float mn = fmaxf(m_i[rg], mx);
            float al = __expf(m_i[rg] - mn);
            float p0 = __expf(sacc[0][rg] - mn);
            float p1 = __expf(sacc[1][rg] - mn);
            float p2 = __expf(sacc[2][rg] - mn);
            float p3 = __expf(sacc[3][rg] - mn);
            float rs = p0 + p1 + p2 + p3;
            #pragma unroll
            for (int msk = 1; msk < 16; msk <<= 1) rs += __shfl_xor(rs, msk);
            l_i[rg] = l_i[rg] * al + rs;
            m_i[rg] = mn;
            #pragma unroll
            for (int dn = 0; dn < 4; ++dn) Oacc[dn][rg] *= al;
            int row = w * 16 + quad * 4 + rg;
            Ps[row][ 0 + fr] = bf16_hi(p0);
            Ps[row][16 + fr] = bf16_hi(p1);
            Ps[row][32 + fr] = bf16_hi(p2);
            Ps[row][48 + fr] = bf16_hi(p3);
        }
        // stage V^T tile (rows = d, cols = s-window) into K buffers
        #pragma unroll
        for (int it = 0; it < 2; ++it) {
            int idx = tid + it * 256;
            int r = idx >> 3, c = (idx & 7) * 8;
            *(uint4*)&Kh[r][c] = *(const uint4*)(vthg + vbase + (size_t)r * 1024 + st * 64 + c);
            *(uint4*)&Kl[r][c] = *(const uint4*)(vtlg + vbase + (size_t)r * 1024 + st * 64 + c);
        }
        __syncthreads();
        // O += P V  (A = P wave-private strip, B = V^T staged)
        #pragma unroll
        for (int kk = 0; kk < 2; ++kk) {
            bf16x8 pa = *(const bf16x8*)&Ps[w * 16 + fr][fq + kk * 32];
            #pragma unroll
            for (int dn = 0; dn < 4; ++dn) {
                bf16x8 vbh = *(const bf16x8*)&Kh[dn * 16 + fr][fq + kk * 32];
                bf16x8 vbl = *(const bf16x8*)&Kl[dn * 16 + fr][fq + kk * 32];
                Oacc[dn] = __builtin_amdgcn_mfma_f32_16x16x32_bf16(pa, vbh, Oacc[dn], 0, 0, 0);
                Oacc[dn] = __builtin_amdgcn_mfma_f32_16x16x32_bf16(pa, vbl, Oacc[dn], 0, 0, 0);
            }
        }
        __syncthreads();   // V/P reads done before next stage overwrites
    }
    // epilogue: normalize, sigmoid gate, split-store y
    float inv[4];
    #pragma unroll
    for (int rg = 0; rg < 4; ++rg) inv[rg] = 1.0f / l_i[rg];
    #pragma unroll
    for (int dn = 0; dn < 4; ++dn) {
        int ch = h * 64 + dn * 16 + fr;
        #pragma unroll
        for (int rg = 0; rg < 4; ++rg) {
            int tok = b * 1024 + qt * 64 + w * 16 + quad * 4 + rg;
            float gv = bf16_f(gbf[(size_t)tok * 768 + ch]);
            float sg = 1.0f / (1.0f + __expf(-gv));
            float val = Oacc[dn][rg] * inv[rg] * sg;
            unsigned short hh, ll;
            split_bf16(val, hh, ll);
            yh[(size_t)tok * 768 + ch] = hh;
            yl[(size_t)tok * 768 + ch] = ll;
        }
    }
}

// ---------------------------------------------------------------------------
// Kernel 4: out = y @ Wo^T + bo -> (B, C, T), split-bf16 MFMA.
// ---------------------------------------------------------------------------
__global__ __launch_bounds__(256, 2) void out_mfma(
    const unsigned short* __restrict__ yh, const unsigned short* __restrict__ yl,
    const unsigned short* __restrict__ woh, const unsigned short* __restrict__ wol,
    const float* __restrict__ bo, float* __restrict__ out) {
    int bx = blockIdx.x;   // c tile 0..5
    int by = blockIdx.y;   // t tile 0..63
    int m0 = bx * 128;     // c
    int n0 = by * 128;     // t

    __shared__ unsigned short Ah[128][40], Al[128][40];
    __shared__ unsigned short Bh[128][40], Bl[128][40];

    int tid  = threadIdx.x;
    int lane = tid & 63, wid = tid >> 6;
    int wm = (wid & 1) * 64, wn = (wid >> 1) * 64;
    int fr = lane & 15, fq = (lane >> 4) * 8;

    f32x4 acc[4][4];
    #pragma unroll
    for (int i = 0; i < 4; ++i)
        #pragma unroll
        for (int j = 0; j < 4; ++j)
            acc[i][j] = (f32x4){0.f, 0.f, 0.f, 0.f};

    int sr = tid >> 1;
    int sc = (tid & 1) * 16;
    const unsigned short* pAh = woh + (size_t)(m0 + sr) * 768 + sc;
    const unsigned short* pAl = wol + (size_t)(m0 + sr) * 768 + sc;
    const unsigned short* pBh = yh  + (size_t)(n0 + sr) * 768 + sc;
    const unsigned short* pBl = yl  + (size_t)(n0 + sr) * 768 + sc;

    for (int k0 = 0; k0 < 768; k0 += 32) {
        uint4 a0 = *(const uint4*)(pAh + k0);
        uint4 a1 = *(const uint4*)(pAh + k0 + 8);
        uint4 b0 = *(const uint4*)(pAl + k0);
        uint4 b1 = *(const uint4*)(pAl + k0 + 8);
        uint4 c0 = *(const uint4*)(pBh + k0);
        uint4 c1 = *(const uint4*)(pBh + k0 + 8);
        uint4 d0 = *(const uint4*)(pBl + k0);
        uint4 d1 = *(const uint4*)(pBl + k0 + 8);
        *(uint4*)&Ah[sr][sc]     = a0;
        *(uint4*)&Ah[sr][sc + 8] = a1;
        *(uint4*)&Al[sr][sc]     = b0;
        *(uint4*)&Al[sr][sc + 8] = b1;
        *(uint4*)&Bh[sr][sc]     = c0;
        *(uint4*)&Bh[sr][sc + 8] = c1;
        *(uint4*)&Bl[sr][sc]     = d0;
        *(uint4*)&Bl[sr][sc + 8] = d1;
        __syncthreads();
        bf16x8 ah[4], al[4], bh[4], bl[4];
        #pragma unroll
        for (int i = 0; i < 4; ++i) {
            ah[i] = *(const bf16x8*)&Ah[wm + i * 16 + fr][fq];
            al[i] = *(const bf16x8*)&Al[wm + i * 16 + fr][fq];
            bh[i] = *(const bf16x8*)&Bh[wn + i * 16 + fr][fq];
            bl[i] = *(const bf16x8*)&Bl[wn + i * 16 + fr][fq];
        }
        #pragma unroll
        for (int mi = 0; mi < 4; ++mi)
            #pragma unroll
            for (int ni = 0; ni < 4; ++ni) {
                acc[mi][ni] = __builtin_amdgcn_mfma_f32_16x16x32_bf16(ah[mi], bh[ni], acc[mi][ni], 0, 0, 0);
                acc[mi][ni] = __builtin_amdgcn_mfma_f32_16x16x32_bf16(ah[mi], bl[ni], acc[mi][ni], 0, 0, 0);
                acc[mi][ni] = __builtin_amdgcn_mfma_f32_16x16x32_bf16(al[mi], bh[ni], acc[mi][ni], 0, 0, 0);
            }
        __syncthreads();
    }
    int rq = (lane >> 4) * 4;
    int bb = n0 >> 10;
    #pragma unroll
    for (int ni = 0; ni < 4; ++ni) {
        int colg = n0 + wn + ni * 16 + fr;
        int tl = colg & 1023;
        #pragma unroll
        for (int mi = 0; mi < 4; ++mi) {
            int row = m0 + wm + mi * 16 + rq;
            #pragma unroll
            for (int rg = 0; rg < 4; ++rg) {
                float val = acc[mi][ni][rg] + bo[row + rg];
                out[((size_t)bb * 768 + row + rg) * 1024 + tl] = val;
            }
        }
    }
}

extern "C" void kernel_launch(void* const* d_in, const int* in_sizes, int n_in,
                              void* d_out, int out_size, void* d_ws, size_t ws_size,
                              hipStream_t stream) {
    const float* x     = (const float*)d_in[0];
    const float* Wq    = (const float*)d_in[1];
    const float* bq    = (const float*)d_in[2];
    const float* Wk    = (const float*)d_in[3];
    const float* bk    = (const float*)d_in[4];
    const float* Wv    = (const float*)d_in[5];
    const float* bv    = (const float*)d_in[6];
    const float* Wo    = (const float*)d_in[7];
    const float* bo    = (const float*)d_in[8];
    const float* Wg    = (const float*)d_in[9];
    const float* bg    = (const float*)d_in[10];
    const float* gamma = (const float*)d_in[11];
    const float* beta  = (const float*)d_in[12];
    float* out = (float*)d_out;

    // workspace (all bf16/ushort): xn_h|xn_l|qh|ql|kh|kl|vth|vtl|g | wbuf
    const size_t S = (size_t)BT_ * C_;
    unsigned short* xn_hi = (unsigned short*)d_ws;
    unsigned short* xn_lo = xn_hi + S;
    unsigned short* qh    = xn_lo + S;
    unsigned short* ql    = qh + S;
    unsigned short* kh    = ql + S;
    unsigned short* kl    = kh + S;
    unsigned short* vth   = kl + S;
    unsigned short* vtl   = vth + S;
    unsigned short* g_bf  = vtl + S;
    unsigned short* wbuf  = g_bf + S;   // [Wq,Wk,Wv,Wg,Wo] x {hi,lo}
    unsigned short* y_hi  = xn_hi;      // alias: xn dead after qkvg
    unsigned short* y_lo  = xn_lo;

    const float* wsrc[5] = {Wq, Wk, Wv, Wg, Wo};
    for (int i = 0; i < 5; ++i)
        wconv_kernel<<<WSZ / 1024, 256, 0, stream>>>(
            wsrc[i], wbuf + (size_t)i * 2 * WSZ, wbuf + (size_t)(i * 2 + 1) * WSZ);

    ln_kernel<<<BT_, 256, 0, stream>>>(x, gamma, beta, xn_hi, xn_lo);
    qkvg_mfma<<<dim3(64, 24), 256, 0, stream>>>(xn_hi, xn_lo, wbuf,
                                                bq, bk, bv, bg,
                                                qh, ql, kh, kl, vth, vtl, g_bf);
    attn_mfma<<<dim3(16, 12, 8), 256, 0, stream>>>(qh, ql, kh, kl, vth, vtl,
                                                   g_bf, y_hi, y_lo);
    out_mfma<<<dim3(6, 64), 256, 0, stream>>>(y_hi, y_lo,
                                              wbuf + (size_t)8 * WSZ,
                                              wbuf + (size_t)9 * WSZ, bo, out);
}